// Round 9
// baseline (1151.824 us; speedup 1.0000x reference)
//
#include <hip/hip_runtime.h>

typedef unsigned short u16;
typedef __attribute__((ext_vector_type(8))) short short8;
typedef __attribute__((ext_vector_type(4))) float f32x4;

__device__ __forceinline__ u16 f2b(float f){
    unsigned u = __builtin_bit_cast(unsigned, f);
    u += 0x7fffu + ((u >> 16) & 1u);   // RNE
    return (u16)(u >> 16);
}
__device__ __forceinline__ float b2f(u16 s){
    unsigned u = ((unsigned)s) << 16;
    return __builtin_bit_cast(float, u);
}
__device__ __forceinline__ float sigm(float x){ return 1.f/(1.f + __expf(-x)); }
// branch-free tanh: 1 - 2/(1+e^{2x})
__device__ __forceinline__ float tanhf2(float x){
    float e = __expf(2.f * x);
    return 1.f - 2.f/(1.f + e);
}

// ---------------- fp32 -> bf16 conversion ----------------
__global__ __launch_bounds__(256) void cvt_bf16(const float* __restrict__ s,
                                                u16* __restrict__ d, int n4){
    int i = blockIdx.x*256 + threadIdx.x;
    if (i < n4){
        float4 v = ((const float4*)s)[i];
        ushort4 o;
        o.x = f2b(v.x); o.y = f2b(v.y); o.z = f2b(v.z); o.w = f2b(v.w);
        ((ushort4*)d)[i] = o;
    }
}

// ---- W_ih cvt with row permutation: out row (unit*4+gate) = in row (gate*128+unit) ----
__global__ __launch_bounds__(192) void cvt_wih_perm(const float* __restrict__ s,
                                                    u16* __restrict__ d){
    int r = blockIdx.x;               // 0..511 input row
    int j = threadIdx.x;              // 0..191 float4 within row
    int g = r >> 7, u = r & 127;
    int ro = u * 4 + g;
    float4 v = ((const float4*)(s + (size_t)r * 768))[j];
    ushort4 o;
    o.x = f2b(v.x); o.y = f2b(v.y); o.z = f2b(v.z); o.w = f2b(v.w);
    ((ushort4*)(d + (size_t)ro * 768))[j] = o;
}

// ---- W_hh cvt with the same row permutation, 128 cols, bf16 out ----
__global__ __launch_bounds__(256) void cvt_whh_perm(const float* __restrict__ s,
                                                    u16* __restrict__ d){
    int idx = blockIdx.x*256 + threadIdx.x;   // 0..16383
    if (idx >= 512*32) return;
    int r = idx >> 5, j = idx & 31;           // row, float4 within row
    int g = r >> 7, u = r & 127;
    int ro = u * 4 + g;
    float4 v = ((const float4*)(s + (size_t)r * 128))[j];
    ushort4 o;
    o.x = f2b(v.x); o.y = f2b(v.y); o.z = f2b(v.z); o.w = f2b(v.w);
    ((ushort4*)(d + (size_t)ro * 128))[j] = o;
}

// ---------------- embedding-gather + input projection GEMM ----------------
// pre written in the LANE-EXACT layout of the C=4 lstm_rec:
//   idx = ((blk*Tdim + t)*512 + wL*64 + cL*16 + uL)*4 + gate   (u16 units)
// where unit uu = wL*16 + uL, chain-in-block cL, gate 0..3.
// word: blk = dir*8  + (batch>>2), cL = batch&3, Tdim=1024
// sent: blk = dir*128 + (sent>>2), cL = sent&3,  Tdim=64
__global__ __launch_bounds__(256) void gemm_embed(
    const u16* __restrict__ E, const int* __restrict__ tok,
    const u16* __restrict__ Wt, const float* __restrict__ bf_,
    const float* __restrict__ bb_, u16* __restrict__ pre, int sentMode)
{
    __shared__ __align__(16) u16 Asm[128*32];
    __shared__ __align__(16) u16 Bsm[128*32];
    const int m0 = blockIdx.x * 128, n0 = blockIdx.y * 128;
    const int tid = threadIdx.x;
    const int ar = tid >> 2, ch = (tid & 3) * 8;
    const u16* ap0 = E + (size_t)tok[m0 + ar] * 768 + ch;
    const u16* ap1 = E + (size_t)tok[m0 + 64 + ar] * 768 + ch;
    const u16* bp0 = Wt + (size_t)(n0 + ar) * 768 + ch;
    const u16* bp1 = Wt + (size_t)(n0 + 64 + ar) * 768 + ch;
    const int lane = tid & 63, wave = tid >> 6;
    const int wm = (wave >> 1) * 64, wn = (wave & 1) * 64;
    const int qr = lane >> 4, lr = lane & 15;
    f32x4 acc[4][4] = {};
    for (int k0 = 0; k0 < 768; k0 += 32){
        __syncthreads();
        *(short8*)&Asm[ar*32 + ch]      = *(const short8*)(ap0 + k0);
        *(short8*)&Asm[(64+ar)*32 + ch] = *(const short8*)(ap1 + k0);
        *(short8*)&Bsm[ar*32 + ch]      = *(const short8*)(bp0 + k0);
        *(short8*)&Bsm[(64+ar)*32 + ch] = *(const short8*)(bp1 + k0);
        __syncthreads();
        short8 af[4], bfr[4];
        #pragma unroll
        for (int i = 0; i < 4; ++i){
            af[i]  = *(const short8*)&Asm[(wm + i*16 + lr)*32 + qr*8];
            bfr[i] = *(const short8*)&Bsm[(wn + i*16 + lr)*32 + qr*8];
        }
        #pragma unroll
        for (int i = 0; i < 4; ++i)
            #pragma unroll
            for (int j = 0; j < 4; ++j)
                acc[i][j] = __builtin_amdgcn_mfma_f32_16x16x32_bf16(af[i], bfr[j], acc[i][j], 0, 0, 0);
    }
    #pragma unroll
    for (int j = 0; j < 4; ++j){
        int col = n0 + wn + j*16 + lr;
        int dirO = col >> 9, pcol = col & 511;
        int uu = pcol >> 2, gg = pcol & 3;
        float bias = (dirO ? bb_ : bf_)[gg*128 + uu];
        int wL = uu >> 4, uL = uu & 15;
        #pragma unroll
        for (int i = 0; i < 4; ++i){
            #pragma unroll
            for (int r = 0; r < 4; ++r){
                int mrow = m0 + wm + i*16 + qr*4 + r;
                int blk, t, cL, Tdim;
                if (sentMode){ int s = mrow >> 6;  t = mrow & 63;   blk = (dirO<<7) + (s >> 2); cL = s & 3; Tdim = 64; }
                else         { int b = mrow >> 10; t = mrow & 1023; blk = (dirO<<3) + (b >> 2); cL = b & 3; Tdim = 1024; }
                size_t idx = (((size_t)blk * Tdim + t) * 512 + (wL*64 + cL*16 + uL)) * 4 + gg;
                pre[idx] = f2b(acc[i][j][r] + bias);
            }
        }
    }
}

// ---------------- batched MFMA LSTM recurrence (C=4 chains/block) ----------------
// r8 (726us, 1700cyc/step) fixed CU starvation; r9 attacks the two measured
// residuals:
//  (1) LDS traffic/conflicts (SQ_LDS_BANK_CONFLICT 5.77M): the bfr b128 reads
//      fetched ALL 16 hb rows though only rows 0-3 (chains) are valid -> now
//      exec-masked to lr<4 (B cols 4-15 feed ignored C cols; lanes lr>=4 keep a
//      zero fragment). hb swizzle re-derived: elem = k ^ (chain<<4) puts the 4
//      chain-rows at bank bases {0,8,16,24} -> write AND masked read are
//      conflict-free (old layout: 8 lanes/bank write, 8 lanes/group read).
//  (2) per-step scalar global store kept an HBM store in every step's vmcnt
//      chain -> h now accumulates in a 16-slot f32 LDS hist (32KB), flushed
//      every 8 steps with coalesced float4 stores (r4-proven geometry, no
//      trailing barrier thanks to 16-slot double-buffering). The step loop's
//      only VMEM is the single pre load -> clean counted vmcnt(3).
__global__ __launch_bounds__(512)
__attribute__((amdgpu_waves_per_eu(2)))
void lstm_rec(
    const u16* __restrict__ preW, const u16* __restrict__ preS,
    const u16* __restrict__ Whp,     // [4][512][128] bf16: wordF, wordB, sentF, sentB
    float* __restrict__ fo, float* __restrict__ fs)
{
    const int bg = blockIdx.x;
    const u16* preBlk; const u16* wh; float* out;
    int T, dir, grpb;
    if (bg < 16){                     // word: 8 groups x 2 dirs, T=1024
        dir = bg >> 3; grpb = bg & 7; T = 1024;
        preBlk = preW + (size_t)bg * 1024 * 2048;
        wh = Whp + (size_t)dir*512*128; out = fo;
    } else {                          // sent: 128 groups x 2 dirs, T=64
        int sg = bg - 16; dir = sg >> 7; grpb = sg & 127; T = 64;
        preBlk = preS + (size_t)sg * 64 * 2048;
        wh = Whp + (size_t)(2+dir)*512*128; out = fs;
    }
    const int tid  = threadIdx.x;
    const int w    = tid >> 6, lane = tid & 63;
    const int lr = lane & 15, qr = lane >> 4;
    const int t0 = dir ? (T-1) : 0;
    const int dt = dir ? -1 : 1;

    // A-fragments: 64 W_hh rows per wave, PINNED in VGPRs (r6-proven pattern)
    short8 aw[4][4];
    #pragma unroll
    for (int i = 0; i < 4; ++i)
        #pragma unroll
        for (int kk = 0; kk < 4; ++kk)
            asm volatile("global_load_dwordx4 %0, %1, off"
                         : "=v"(aw[i][kk])
                         : "v"(wh + (size_t)(w*64 + i*16 + lr)*128 + kk*32 + qr*8));
    asm volatile("s_waitcnt vmcnt(0)");
    __builtin_amdgcn_sched_barrier(0);

    __shared__ __align__(16) u16    hb[2][512];    // bf16 h, 4 chain-rows x 128 k (2KB)
    __shared__ __align__(16) float4 rd[512];       // per-wave gate redistribution (8KB)
    __shared__ __align__(16) float  hist[16*512];  // h history, 16 slots (32KB)
    for (int k = tid; k < 1024; k += 512) ((u16*)hb)[k] = 0;

    // gate-lane identity: chain cL = lane>>4 (0..3), unit u = w*16 + (lane&15)
    const int cL = lane >> 4;
    const int ur = lane & 15;
    const int u  = w*16 + ur;

    // pre prefetch: 4 static slots, compiler-visible (counted vmcnt)
    const long pstep = (long)dt * 2048;
    const u16* p = preBlk + (long)t0 * 2048 + tid*4;
    ushort4 buf[4];
    buf[0] = *(const ushort4*)p;
    buf[1] = *(const ushort4*)(p + pstep);
    buf[2] = *(const ushort4*)(p + 2*pstep);
    p += 3*pstep;

    // LDS addresses
    const int rdW0 = w*64 + lr*16;                 // redist write base (lr = chain, lanes lr<4)
    const int rdR  = w*64 + cL*16 + (ur ^ (cL<<2));// redist read slot
    const int hbW  = cL*128 + (u ^ (cL<<4));       // swizzled hb write (u16 idx, bank-free)
    const int rxor = lr << 4;                      // bfr read XOR (matches write swizzle)

    float cst = 0.f;
    short8 bfr[4] = {};                            // lanes lr>=4 keep zeros forever
    __syncthreads();

#define LSTM_STEP(J, LOADJ) do {                                              \
    if (lr < 4){                                                              \
        _Pragma("unroll")                                                     \
        for (int kk = 0; kk < 4; ++kk)                                        \
            bfr[kk] = *(const short8*)&hb[(J)&1][lr*128 + ((((kk)*4+qr)<<3) ^ rxor)]; \
    }                                                                         \
    buf[LOADJ] = *(const ushort4*)p;                                          \
    p += pstep;                                                               \
    f32x4 acc[4] = {};                                                        \
    _Pragma("unroll")                                                         \
    for (int i = 0; i < 4; ++i)                                               \
        _Pragma("unroll")                                                     \
        for (int kk = 0; kk < 4; ++kk)                                        \
            acc[i] = __builtin_amdgcn_mfma_f32_16x16x32_bf16(aw[i][kk], bfr[kk], acc[i], 0, 0, 0); \
    if (lr < 4){                                                              \
        _Pragma("unroll")                                                     \
        for (int i = 0; i < 4; ++i)                                           \
            rd[rdW0 + ((i*4+qr) ^ (lr<<2))] = __builtin_bit_cast(float4, acc[i]); \
    }                                                                         \
    float4 g4 = rd[rdR];                                                      \
    ushort4 pc = buf[J];                                                      \
    float a0 = b2f(pc.x) + g4.x, a1 = b2f(pc.y) + g4.y;                       \
    float a2 = b2f(pc.z) + g4.z, a3 = b2f(pc.w) + g4.w;                       \
    float gi = sigm(a0), gf = sigm(a1);                                       \
    float gg = tanhf2(a2), go = sigm(a3);                                     \
    float c = gf*cst + gi*gg; cst = c;                                        \
    float h = go*tanhf2(c);                                                   \
    hist[(ib15 + (J))*512 + tid] = h;                                         \
    hb[((J)&1)^1][hbW] = f2b(h);                                              \
    __builtin_amdgcn_sched_barrier(0);                                        \
    asm volatile("s_waitcnt lgkmcnt(0)");                                     \
    __builtin_amdgcn_s_barrier();                                             \
    __builtin_amdgcn_sched_barrier(0);                                        \
} while(0)

    for (int itBase = 0; itBase < T; itBase += 4){
        const int ib15 = itBase & 15;
        LSTM_STEP(0, 3);
        LSTM_STEP(1, 0);
        LSTM_STEP(2, 1);
        LSTM_STEP(3, 2);
        if ((itBase & 7) == 4){
            // coalesced flush of steps [itBase-8+4 .. itBase+3]: slots fb..fb+7.
            // Writers' next 8 slots are the OTHER half -> no trailing barrier.
            const int fBase = itBase - 4;
            const int fb = fBase & 15;
            #pragma unroll
            for (int j2 = 0; j2 < 2; ++j2){
                int lin  = j2*512 + tid;        // 0..1023
                int s    = lin >> 7;            // 0..7 (slot within window)
                int quad = lin & 127;           // float4 cell-group within slot
                int wq = quad >> 4;             // wave part of unit
                int cq = (quad >> 2) & 3;       // chain
                int uq = (quad & 3) * 4;        // unit low bits (x4)
                float4 v = *(const float4*)&hist[((fb + s) & 15)*512 + quad*4];
                int tt = t0 + dt*(fBase + s);
                *(float4*)(out + ((size_t)(grpb*4 + cq)*T + tt)*256 + dir*128 + wq*16 + uq) = v;
            }
        }
    }
#undef LSTM_STEP
}

// ---------------- gate GEMM + blend epilogue ----------------
// gamma = sigmoid([fo|fs] @ gW^T + gb); out = gamma*fo + (1-gamma)*fs
__global__ __launch_bounds__(256) void gemm_gate(
    const u16* __restrict__ gW, const float* __restrict__ gb,
    const float* __restrict__ fo, const float* __restrict__ fs,
    float* __restrict__ out)
{
    __shared__ __align__(16) u16 Asm[128*32];
    __shared__ __align__(16) u16 Bsm[128*32];
    const int m0 = blockIdx.x * 128, n0 = blockIdx.y * 128;
    const int tid = threadIdx.x;
    const int ar = tid >> 2, ch = (tid & 3) * 8;
    const float* af0 = fo + (size_t)(m0 + ar) * 256 + ch;
    const float* af1 = fo + (size_t)(m0 + 64 + ar) * 256 + ch;
    const float* as0 = fs + (size_t)(m0 + ar) * 256 + ch;
    const float* as1 = fs + (size_t)(m0 + 64 + ar) * 256 + ch;
    const u16* bp0 = gW + (size_t)(n0 + ar) * 512 + ch;
    const u16* bp1 = gW + (size_t)(n0 + 64 + ar) * 512 + ch;
    const int lane = tid & 63, wave = tid >> 6;
    const int wm = (wave >> 1) * 64, wn = (wave & 1) * 64;
    const int qr = lane >> 4, lr = lane & 15;
    f32x4 acc[4][4] = {};
    for (int k0 = 0; k0 < 512; k0 += 32){
        __syncthreads();
        const float* s0 = (k0 < 256) ? (af0 + k0) : (as0 + (k0 - 256));
        const float* s1 = (k0 < 256) ? (af1 + k0) : (as1 + (k0 - 256));
        float4 x0 = ((const float4*)s0)[0], x1 = ((const float4*)s0)[1];
        float4 y0 = ((const float4*)s1)[0], y1 = ((const float4*)s1)[1];
        ushort4 a0; a0.x=f2b(x0.x); a0.y=f2b(x0.y); a0.z=f2b(x0.z); a0.w=f2b(x0.w);
        ushort4 a1; a1.x=f2b(x1.x); a1.y=f2b(x1.y); a1.z=f2b(x1.z); a1.w=f2b(x1.w);
        ushort4 b0; b0.x=f2b(y0.x); b0.y=f2b(y0.y); b0.z=f2b(y0.z); b0.w=f2b(y0.w);
        ushort4 b1; b1.x=f2b(y1.x); b1.y=f2b(y1.y); b1.z=f2b(y1.z); b1.w=f2b(y1.w);
        *(ushort4*)&Asm[ar*32 + ch]          = a0;
        *(ushort4*)&Asm[ar*32 + ch + 4]      = a1;
        *(ushort4*)&Asm[(64+ar)*32 + ch]     = b0;
        *(ushort4*)&Asm[(64+ar)*32 + ch + 4] = b1;
        *(short8*)&Bsm[ar*32 + ch]      = *(const short8*)(bp0 + k0);
        *(short8*)&Bsm[(64+ar)*32 + ch] = *(const short8*)(bp1 + k0);
        __syncthreads();
        short8 af[4], bfr[4];
        #pragma unroll
        for (int i = 0; i < 4; ++i){
            af[i]  = *(const short8*)&Asm[(wm + i*16 + lr)*32 + qr*8];
            bfr[i] = *(const short8*)&Bsm[(wn + i*16 + lr)*32 + qr*8];
        }
        #pragma unroll
        for (int i = 0; i < 4; ++i)
            #pragma unroll
            for (int j = 0; j < 4; ++j)
                acc[i][j] = __builtin_amdgcn_mfma_f32_16x16x32_bf16(af[i], bfr[j], acc[i][j], 0, 0, 0);
    }
    #pragma unroll
    for (int j = 0; j < 4; ++j){
        int col = n0 + wn + j*16 + lr;   // 0..255
        float bias = gb[col];
        #pragma unroll
        for (int i = 0; i < 4; ++i){
            #pragma unroll
            for (int r = 0; r < 4; ++r){
                int row = m0 + wm + i*16 + qr*4 + r;
                size_t o = (size_t)row*256 + col;
                float gamma = sigm(acc[i][j][r] + bias);
                out[o] = gamma * fo[o] + (1.f - gamma) * fs[o];
            }
        }
    }
}

extern "C" void kernel_launch(void* const* d_in, const int* in_sizes, int n_in,
                              void* d_out, int out_size, void* d_ws, size_t ws_size,
                              hipStream_t stream)
{
    (void)in_sizes; (void)n_in; (void)out_size; (void)ws_size;
    const int*   wordTok = (const int*)d_in[0];
    const int*   sentTok = (const int*)d_in[1];
    const float* E       = (const float*)d_in[3];
    const float* WihWf   = (const float*)d_in[4];
    const float* WhhWf   = (const float*)d_in[5];
    const float* bWf     = (const float*)d_in[6];
    const float* WihWb   = (const float*)d_in[7];
    const float* WhhWb   = (const float*)d_in[8];
    const float* bWb     = (const float*)d_in[9];
    const float* WihSf   = (const float*)d_in[10];
    const float* WhhSf   = (const float*)d_in[11];
    const float* bSf     = (const float*)d_in[12];
    const float* WihSb   = (const float*)d_in[13];
    const float* WhhSb   = (const float*)d_in[14];
    const float* bSb     = (const float*)d_in[15];
    const float* gateW   = (const float*)d_in[16];
    const float* gateB   = (const float*)d_in[17];
    float* out = (float*)d_out;

    char* w = (char*)d_ws;
    u16* Eb   = (u16*)w;  w += (size_t)30522*768*2;
    u16* Ww   = (u16*)w;  w += (size_t)1024*768*2;
    u16* Ws_  = (u16*)w;  w += (size_t)1024*768*2;
    u16* gWb  = (u16*)w;  w += (size_t)256*512*2;
    u16* preW = (u16*)w;  w += (size_t)32768*1024*2;
    u16* preS = (u16*)w;  w += (size_t)32768*1024*2;
    float* fo = (float*)w; w += (size_t)32768*256*4;
    float* fs = (float*)w; w += (size_t)32768*256*4;
    u16* Whp  = (u16*)w;  w += (size_t)4*512*128*2;

    const int nE4 = 30522*768/4;
    cvt_bf16<<<(nE4+255)/256, 256, 0, stream>>>(E, Eb, nE4);
    cvt_wih_perm<<<512, 192, 0, stream>>>(WihWf, Ww);
    cvt_wih_perm<<<512, 192, 0, stream>>>(WihWb, Ww + 512*768);
    cvt_wih_perm<<<512, 192, 0, stream>>>(WihSf, Ws_);
    cvt_wih_perm<<<512, 192, 0, stream>>>(WihSb, Ws_ + 512*768);
    const int nG4 = 256*512/4;
    cvt_bf16<<<(nG4+255)/256, 256, 0, stream>>>(gateW, gWb, nG4);
    cvt_whh_perm<<<64, 256, 0, stream>>>(WhhWf, Whp);
    cvt_whh_perm<<<64, 256, 0, stream>>>(WhhWb, Whp + 512*128);
    cvt_whh_perm<<<64, 256, 0, stream>>>(WhhSf, Whp + 2*512*128);
    cvt_whh_perm<<<64, 256, 0, stream>>>(WhhSb, Whp + 3*512*128);

    gemm_embed<<<dim3(256,8), 256, 0, stream>>>(Eb, wordTok, Ww, bWf, bWb, preW, 0);
    gemm_embed<<<dim3(256,8), 256, 0, stream>>>(Eb, sentTok, Ws_, bSf, bSb, preS, 1);
    lstm_rec<<<272, 512, 0, stream>>>(preW, preS, Whp, fo, fs);
    gemm_gate<<<dim3(256,2), 256, 0, stream>>>(gWb, gateB, fo, fs, out);
}

// Round 10
// 1094.546 us; speedup vs baseline: 1.0523x; 1.0523x over previous
//
#include <hip/hip_runtime.h>

typedef unsigned short u16;
typedef __attribute__((ext_vector_type(8))) short short8;
typedef __attribute__((ext_vector_type(4))) float f32x4;

__device__ __forceinline__ u16 f2b(float f){
    unsigned u = __builtin_bit_cast(unsigned, f);
    u += 0x7fffu + ((u >> 16) & 1u);   // RNE
    return (u16)(u >> 16);
}
__device__ __forceinline__ float b2f(u16 s){
    unsigned u = ((unsigned)s) << 16;
    return __builtin_bit_cast(float, u);
}
__device__ __forceinline__ float sigm(float x){ return 1.f/(1.f + __expf(-x)); }
// branch-free tanh: 1 - 2/(1+e^{2x})
__device__ __forceinline__ float tanhf2(float x){
    float e = __expf(2.f * x);
    return 1.f - 2.f/(1.f + e);
}

// ---------------- fp32 -> bf16 conversion ----------------
__global__ __launch_bounds__(256) void cvt_bf16(const float* __restrict__ s,
                                                u16* __restrict__ d, int n4){
    int i = blockIdx.x*256 + threadIdx.x;
    if (i < n4){
        float4 v = ((const float4*)s)[i];
        ushort4 o;
        o.x = f2b(v.x); o.y = f2b(v.y); o.z = f2b(v.z); o.w = f2b(v.w);
        ((ushort4*)d)[i] = o;
    }
}

// ---- W_ih cvt with row permutation: out row (unit*4+gate) = in row (gate*128+unit) ----
__global__ __launch_bounds__(192) void cvt_wih_perm(const float* __restrict__ s,
                                                    u16* __restrict__ d){
    int r = blockIdx.x;               // 0..511 input row
    int j = threadIdx.x;              // 0..191 float4 within row
    int g = r >> 7, u = r & 127;
    int ro = u * 4 + g;
    float4 v = ((const float4*)(s + (size_t)r * 768))[j];
    ushort4 o;
    o.x = f2b(v.x); o.y = f2b(v.y); o.z = f2b(v.z); o.w = f2b(v.w);
    ((ushort4*)(d + (size_t)ro * 768))[j] = o;
}

// ---- W_hh cvt with the same row permutation, 128 cols, bf16 out ----
__global__ __launch_bounds__(256) void cvt_whh_perm(const float* __restrict__ s,
                                                    u16* __restrict__ d){
    int idx = blockIdx.x*256 + threadIdx.x;   // 0..16383
    if (idx >= 512*32) return;
    int r = idx >> 5, j = idx & 31;           // row, float4 within row
    int g = r >> 7, u = r & 127;
    int ro = u * 4 + g;
    float4 v = ((const float4*)(s + (size_t)r * 128))[j];
    ushort4 o;
    o.x = f2b(v.x); o.y = f2b(v.y); o.z = f2b(v.z); o.w = f2b(v.w);
    ((ushort4*)(d + (size_t)ro * 128))[j] = o;
}

// ---------------- embedding-gather + input projection GEMM ----------------
// pre written in the LANE-EXACT layout of the column-quadrant lstm_rec:
//   lstm lane (w, qr=lane>>4, lr=lane&15) owns cell (unit = w*16+(lr>>2)*4+qr,
//   chain cL = lr&3) -> tidL = w*64 + qr*16 + lr where lr = (uL&12) | cL,
//   qr = uL&3 (uL = unit&15).  idx = ((blk*Tdim + t)*512 + tidL)*4 + gate.
// word: blk = dir*8  + (batch>>2), cL = batch&3, Tdim=1024
// sent: blk = dir*128 + (sent>>2), cL = sent&3,  Tdim=64
__global__ __launch_bounds__(256) void gemm_embed(
    const u16* __restrict__ E, const int* __restrict__ tok,
    const u16* __restrict__ Wt, const float* __restrict__ bf_,
    const float* __restrict__ bb_, u16* __restrict__ pre, int sentMode)
{
    __shared__ __align__(16) u16 Asm[128*32];
    __shared__ __align__(16) u16 Bsm[128*32];
    const int m0 = blockIdx.x * 128, n0 = blockIdx.y * 128;
    const int tid = threadIdx.x;
    const int ar = tid >> 2, ch = (tid & 3) * 8;
    const u16* ap0 = E + (size_t)tok[m0 + ar] * 768 + ch;
    const u16* ap1 = E + (size_t)tok[m0 + 64 + ar] * 768 + ch;
    const u16* bp0 = Wt + (size_t)(n0 + ar) * 768 + ch;
    const u16* bp1 = Wt + (size_t)(n0 + 64 + ar) * 768 + ch;
    const int lane = tid & 63, wave = tid >> 6;
    const int wm = (wave >> 1) * 64, wn = (wave & 1) * 64;
    const int qr = lane >> 4, lr = lane & 15;
    f32x4 acc[4][4] = {};
    for (int k0 = 0; k0 < 768; k0 += 32){
        __syncthreads();
        *(short8*)&Asm[ar*32 + ch]      = *(const short8*)(ap0 + k0);
        *(short8*)&Asm[(64+ar)*32 + ch] = *(const short8*)(ap1 + k0);
        *(short8*)&Bsm[ar*32 + ch]      = *(const short8*)(bp0 + k0);
        *(short8*)&Bsm[(64+ar)*32 + ch] = *(const short8*)(bp1 + k0);
        __syncthreads();
        short8 af[4], bfr[4];
        #pragma unroll
        for (int i = 0; i < 4; ++i){
            af[i]  = *(const short8*)&Asm[(wm + i*16 + lr)*32 + qr*8];
            bfr[i] = *(const short8*)&Bsm[(wn + i*16 + lr)*32 + qr*8];
        }
        #pragma unroll
        for (int i = 0; i < 4; ++i)
            #pragma unroll
            for (int j = 0; j < 4; ++j)
                acc[i][j] = __builtin_amdgcn_mfma_f32_16x16x32_bf16(af[i], bfr[j], acc[i][j], 0, 0, 0);
    }
    #pragma unroll
    for (int j = 0; j < 4; ++j){
        int col = n0 + wn + j*16 + lr;
        int dirO = col >> 9, pcol = col & 511;
        int uu = pcol >> 2, gg = pcol & 3;
        float bias = (dirO ? bb_ : bf_)[gg*128 + uu];
        int wL = uu >> 4, uL = uu & 15;
        int tidPart = wL*64 + (uL & 3)*16 + (uL & 12);   // + cL at use site
        #pragma unroll
        for (int i = 0; i < 4; ++i){
            #pragma unroll
            for (int r = 0; r < 4; ++r){
                int mrow = m0 + wm + i*16 + qr*4 + r;
                int blk, t, cL, Tdim;
                if (sentMode){ int s = mrow >> 6;  t = mrow & 63;   blk = (dirO<<7) + (s >> 2); cL = s & 3; Tdim = 64; }
                else         { int b = mrow >> 10; t = mrow & 1023; blk = (dirO<<3) + (b >> 2); cL = b & 3; Tdim = 1024; }
                size_t idx = (((size_t)blk * Tdim + t) * 512 + (tidPart + cL)) * 4 + gg;
                pre[idx] = f2b(acc[i][j][r] + bias);
            }
        }
    }
}

// ---------------- batched MFMA LSTM recurrence (column-quadrant layout) ----------------
// r8/r9 evidence: no pipe saturated, step bound by the serial phase chain; the
// rd redistribution round-trip (~300cyc) existed only because all 4 chains sat
// in B cols 0-3. r10: chains occupy cols 4i..4i+3 PER ACC-GROUP i. Since col
// 4i+c of acc[i] depends only on B-frag lanes lr==4i+c, all four MFMAs SHARE
// one B-fragment where lane (qr,lr) holds h[chain lr&3][k=kk*32+qr*8..+7]
// (4-lane broadcast read). Lane (qr,lr) then finds its own cell - all 4 gates
// of (unit w*16+(lr>>2)*4+qr, chain lr&3) - in acc[lr>>2] (selected by
// loop-invariant-mask cndmasks, no runtime indexing). Redistribution DELETED:
// per-wave DS ops 11 -> 5, two LDS latencies off the critical path. h goes
// straight to global (r8-proven; now 1 packed store/lane). hb swizzle
// elem = k ^ (chain<<4): write = 32 banks 1 dword each; read = 2-way = free.
__global__ __launch_bounds__(512)
__attribute__((amdgpu_waves_per_eu(2)))
void lstm_rec(
    const u16* __restrict__ preW, const u16* __restrict__ preS,
    const u16* __restrict__ Whp,     // [4][512][128] bf16: wordF, wordB, sentF, sentB
    float* __restrict__ fo, float* __restrict__ fs)
{
    const int bg = blockIdx.x;
    const u16* preBlk; const u16* wh; float* out;
    int T, dir, grpb;
    if (bg < 16){                     // word: 8 groups x 2 dirs, T=1024
        dir = bg >> 3; grpb = bg & 7; T = 1024;
        preBlk = preW + (size_t)bg * 1024 * 2048;
        wh = Whp + (size_t)dir*512*128; out = fo;
    } else {                          // sent: 128 groups x 2 dirs, T=64
        int sg = bg - 16; dir = sg >> 7; grpb = sg & 127; T = 64;
        preBlk = preS + (size_t)sg * 64 * 2048;
        wh = Whp + (size_t)(2+dir)*512*128; out = fs;
    }
    const int tid  = threadIdx.x;
    const int w    = tid >> 6, lane = tid & 63;
    const int lr = lane & 15, qr = lane >> 4;
    const int t0 = dir ? (T-1) : 0;
    const int dt = dir ? -1 : 1;

    // A-fragments: 64 W_hh rows per wave, PINNED in VGPRs (r6-proven pattern)
    short8 aw[4][4];
    #pragma unroll
    for (int i = 0; i < 4; ++i)
        #pragma unroll
        for (int kk = 0; kk < 4; ++kk)
            asm volatile("global_load_dwordx4 %0, %1, off"
                         : "=v"(aw[i][kk])
                         : "v"(wh + (size_t)(w*64 + i*16 + lr)*128 + kk*32 + qr*8));
    asm volatile("s_waitcnt vmcnt(0)");
    __builtin_amdgcn_sched_barrier(0);

    __shared__ __align__(16) u16 hb[2][512];   // bf16 h: [chain 0..3][unit 0..127], swizzled (2KB)
    for (int k = tid; k < 1024; k += 512) ((u16*)hb)[k] = 0;

    // this lane's cell: chain cL = lr&3, unit u = w*16 + (lr>>2)*4 + qr
    const int cL = lr & 3;
    const int u  = w*16 + (lr >> 2)*4 + qr;
    const int hbW   = cL*128 + (u ^ (cL << 4));          // swizzled h write
    const int rbase = cL*128;                            // bfr read row base
    const int rxor  = cL << 4;                           // bfr read swizzle
    const bool s2 = (lr & 4) != 0, s3 = (lr & 8) != 0;   // acc-select masks (loop-invariant)

    const int chainG = grpb*4 + cL;
    float* po = out + ((size_t)chainG*T + t0)*256 + dir*128 + u;
    const long ostep = (long)dt * 256;

    // pre prefetch: 4 static slots, compiler-visible (counted vmcnt, r5-proven)
    const long pstep = (long)dt * 2048;
    const u16* p = preBlk + (long)t0 * 2048 + tid*4;
    ushort4 buf[4];
    buf[0] = *(const ushort4*)p;
    buf[1] = *(const ushort4*)(p + pstep);
    buf[2] = *(const ushort4*)(p + 2*pstep);
    p += 3*pstep;

    float cst = 0.f;
    __syncthreads();

#define LSTM_STEP(J, LOADJ) do {                                              \
    short8 bfr[4];                                                            \
    _Pragma("unroll")                                                         \
    for (int kk = 0; kk < 4; ++kk)                                            \
        bfr[kk] = *(const short8*)&hb[(J)&1][rbase + ((kk*32 + qr*8) ^ rxor)];\
    buf[LOADJ] = *(const ushort4*)p;                                          \
    p += pstep;                                                               \
    f32x4 a0 = {}, a1 = {}, a2 = {}, a3 = {};                                 \
    _Pragma("unroll")                                                         \
    for (int kk = 0; kk < 4; ++kk){                                           \
        a0 = __builtin_amdgcn_mfma_f32_16x16x32_bf16(aw[0][kk], bfr[kk], a0, 0, 0, 0); \
        a1 = __builtin_amdgcn_mfma_f32_16x16x32_bf16(aw[1][kk], bfr[kk], a1, 0, 0, 0); \
        a2 = __builtin_amdgcn_mfma_f32_16x16x32_bf16(aw[2][kk], bfr[kk], a2, 0, 0, 0); \
        a3 = __builtin_amdgcn_mfma_f32_16x16x32_bf16(aw[3][kk], bfr[kk], a3, 0, 0, 0); \
    }                                                                         \
    float m0 = s3 ? (s2 ? a3[0] : a2[0]) : (s2 ? a1[0] : a0[0]);              \
    float m1 = s3 ? (s2 ? a3[1] : a2[1]) : (s2 ? a1[1] : a0[1]);              \
    float m2 = s3 ? (s2 ? a3[2] : a2[2]) : (s2 ? a1[2] : a0[2]);              \
    float m3 = s3 ? (s2 ? a3[3] : a2[3]) : (s2 ? a1[3] : a0[3]);              \
    ushort4 pc = buf[J];                                                      \
    float g0 = b2f(pc.x) + m0, g1 = b2f(pc.y) + m1;                           \
    float g2 = b2f(pc.z) + m2, g3 = b2f(pc.w) + m3;                           \
    float gi = sigm(g0), gf = sigm(g1);                                       \
    float gg = tanhf2(g2), go = sigm(g3);                                     \
    float c = gf*cst + gi*gg; cst = c;                                        \
    float h = go*tanhf2(c);                                                   \
    po[0] = h;                                                                \
    po += ostep;                                                              \
    hb[((J)&1)^1][hbW] = f2b(h);                                              \
    __builtin_amdgcn_sched_barrier(0);                                        \
    asm volatile("s_waitcnt lgkmcnt(0)");                                     \
    __builtin_amdgcn_s_barrier();                                             \
    __builtin_amdgcn_sched_barrier(0);                                        \
} while(0)

    for (int itBase = 0; itBase < T; itBase += 4){
        LSTM_STEP(0, 3);
        LSTM_STEP(1, 0);
        LSTM_STEP(2, 1);
        LSTM_STEP(3, 2);
    }
#undef LSTM_STEP
}

// ---------------- gate GEMM + blend epilogue ----------------
// gamma = sigmoid([fo|fs] @ gW^T + gb); out = gamma*fo + (1-gamma)*fs
__global__ __launch_bounds__(256) void gemm_gate(
    const u16* __restrict__ gW, const float* __restrict__ gb,
    const float* __restrict__ fo, const float* __restrict__ fs,
    float* __restrict__ out)
{
    __shared__ __align__(16) u16 Asm[128*32];
    __shared__ __align__(16) u16 Bsm[128*32];
    const int m0 = blockIdx.x * 128, n0 = blockIdx.y * 128;
    const int tid = threadIdx.x;
    const int ar = tid >> 2, ch = (tid & 3) * 8;
    const float* af0 = fo + (size_t)(m0 + ar) * 256 + ch;
    const float* af1 = fo + (size_t)(m0 + 64 + ar) * 256 + ch;
    const float* as0 = fs + (size_t)(m0 + ar) * 256 + ch;
    const float* as1 = fs + (size_t)(m0 + 64 + ar) * 256 + ch;
    const u16* bp0 = gW + (size_t)(n0 + ar) * 512 + ch;
    const u16* bp1 = gW + (size_t)(n0 + 64 + ar) * 512 + ch;
    const int lane = tid & 63, wave = tid >> 6;
    const int wm = (wave >> 1) * 64, wn = (wave & 1) * 64;
    const int qr = lane >> 4, lr = lane & 15;
    f32x4 acc[4][4] = {};
    for (int k0 = 0; k0 < 512; k0 += 32){
        __syncthreads();
        const float* s0 = (k0 < 256) ? (af0 + k0) : (as0 + (k0 - 256));
        const float* s1 = (k0 < 256) ? (af1 + k0) : (as1 + (k0 - 256));
        float4 x0 = ((const float4*)s0)[0], x1 = ((const float4*)s0)[1];
        float4 y0 = ((const float4*)s1)[0], y1 = ((const float4*)s1)[1];
        ushort4 a0; a0.x=f2b(x0.x); a0.y=f2b(x0.y); a0.z=f2b(x0.z); a0.w=f2b(x0.w);
        ushort4 a1; a1.x=f2b(x1.x); a1.y=f2b(x1.y); a1.z=f2b(x1.z); a1.w=f2b(x1.w);
        ushort4 b0; b0.x=f2b(y0.x); b0.y=f2b(y0.y); b0.z=f2b(y0.z); b0.w=f2b(y0.w);
        ushort4 b1; b1.x=f2b(y1.x); b1.y=f2b(y1.y); b1.z=f2b(y1.z); b1.w=f2b(y1.w);
        *(ushort4*)&Asm[ar*32 + ch]          = a0;
        *(ushort4*)&Asm[ar*32 + ch + 4]      = a1;
        *(ushort4*)&Asm[(64+ar)*32 + ch]     = b0;
        *(ushort4*)&Asm[(64+ar)*32 + ch + 4] = b1;
        *(short8*)&Bsm[ar*32 + ch]      = *(const short8*)(bp0 + k0);
        *(short8*)&Bsm[(64+ar)*32 + ch] = *(const short8*)(bp1 + k0);
        __syncthreads();
        short8 af[4], bfr[4];
        #pragma unroll
        for (int i = 0; i < 4; ++i){
            af[i]  = *(const short8*)&Asm[(wm + i*16 + lr)*32 + qr*8];
            bfr[i] = *(const short8*)&Bsm[(wn + i*16 + lr)*32 + qr*8];
        }
        #pragma unroll
        for (int i = 0; i < 4; ++i)
            #pragma unroll
            for (int j = 0; j < 4; ++j)
                acc[i][j] = __builtin_amdgcn_mfma_f32_16x16x32_bf16(af[i], bfr[j], acc[i][j], 0, 0, 0);
    }
    #pragma unroll
    for (int j = 0; j < 4; ++j){
        int col = n0 + wn + j*16 + lr;   // 0..255
        float bias = gb[col];
        #pragma unroll
        for (int i = 0; i < 4; ++i){
            #pragma unroll
            for (int r = 0; r < 4; ++r){
                int row = m0 + wm + i*16 + qr*4 + r;
                size_t o = (size_t)row*256 + col;
                float gamma = sigm(acc[i][j][r] + bias);
                out[o] = gamma * fo[o] + (1.f - gamma) * fs[o];
            }
        }
    }
}

extern "C" void kernel_launch(void* const* d_in, const int* in_sizes, int n_in,
                              void* d_out, int out_size, void* d_ws, size_t ws_size,
                              hipStream_t stream)
{
    (void)in_sizes; (void)n_in; (void)out_size; (void)ws_size;
    const int*   wordTok = (const int*)d_in[0];
    const int*   sentTok = (const int*)d_in[1];
    const float* E       = (const float*)d_in[3];
    const float* WihWf   = (const float*)d_in[4];
    const float* WhhWf   = (const float*)d_in[5];
    const float* bWf     = (const float*)d_in[6];
    const float* WihWb   = (const float*)d_in[7];
    const float* WhhWb   = (const float*)d_in[8];
    const float* bWb     = (const float*)d_in[9];
    const float* WihSf   = (const float*)d_in[10];
    const float* WhhSf   = (const float*)d_in[11];
    const float* bSf     = (const float*)d_in[12];
    const float* WihSb   = (const float*)d_in[13];
    const float* WhhSb   = (const float*)d_in[14];
    const float* bSb     = (const float*)d_in[15];
    const float* gateW   = (const float*)d_in[16];
    const float* gateB   = (const float*)d_in[17];
    float* out = (float*)d_out;

    char* w = (char*)d_ws;
    u16* Eb   = (u16*)w;  w += (size_t)30522*768*2;
    u16* Ww   = (u16*)w;  w += (size_t)1024*768*2;
    u16* Ws_  = (u16*)w;  w += (size_t)1024*768*2;
    u16* gWb  = (u16*)w;  w += (size_t)256*512*2;
    u16* preW = (u16*)w;  w += (size_t)32768*1024*2;
    u16* preS = (u16*)w;  w += (size_t)32768*1024*2;
    float* fo = (float*)w; w += (size_t)32768*256*4;
    float* fs = (float*)w; w += (size_t)32768*256*4;
    u16* Whp  = (u16*)w;  w += (size_t)4*512*128*2;

    const int nE4 = 30522*768/4;
    cvt_bf16<<<(nE4+255)/256, 256, 0, stream>>>(E, Eb, nE4);
    cvt_wih_perm<<<512, 192, 0, stream>>>(WihWf, Ww);
    cvt_wih_perm<<<512, 192, 0, stream>>>(WihWb, Ww + 512*768);
    cvt_wih_perm<<<512, 192, 0, stream>>>(WihSf, Ws_);
    cvt_wih_perm<<<512, 192, 0, stream>>>(WihSb, Ws_ + 512*768);
    const int nG4 = 256*512/4;
    cvt_bf16<<<(nG4+255)/256, 256, 0, stream>>>(gateW, gWb, nG4);
    cvt_whh_perm<<<64, 256, 0, stream>>>(WhhWf, Whp);
    cvt_whh_perm<<<64, 256, 0, stream>>>(WhhWb, Whp + 512*128);
    cvt_whh_perm<<<64, 256, 0, stream>>>(WhhSf, Whp + 2*512*128);
    cvt_whh_perm<<<64, 256, 0, stream>>>(WhhSb, Whp + 3*512*128);

    gemm_embed<<<dim3(256,8), 256, 0, stream>>>(Eb, wordTok, Ww, bWf, bWb, preW, 0);
    gemm_embed<<<dim3(256,8), 256, 0, stream>>>(Eb, sentTok, Ws_, bSf, bSb, preS, 1);
    lstm_rec<<<272, 512, 0, stream>>>(preW, preS, Whp, fo, fs);
    gemm_gate<<<dim3(256,2), 256, 0, stream>>>(gWb, gateB, fo, fs, out);
}

// Round 12
// 1064.685 us; speedup vs baseline: 1.0818x; 1.0280x over previous
//
#include <hip/hip_runtime.h>

typedef unsigned short u16;
typedef __attribute__((ext_vector_type(8))) short short8;
typedef __attribute__((ext_vector_type(4))) float f32x4;

__device__ __forceinline__ u16 f2b(float f){
    unsigned u = __builtin_bit_cast(unsigned, f);
    u += 0x7fffu + ((u >> 16) & 1u);   // RNE
    return (u16)(u >> 16);
}
__device__ __forceinline__ float b2f(u16 s){
    unsigned u = ((unsigned)s) << 16;
    return __builtin_bit_cast(float, u);
}
__device__ __forceinline__ float sigm(float x){ return 1.f/(1.f + __expf(-x)); }
// branch-free tanh: 1 - 2/(1+e^{2x})
__device__ __forceinline__ float tanhf2(float x){
    float e = __expf(2.f * x);
    return 1.f - 2.f/(1.f + e);
}

// ---------------- fp32 -> bf16 conversion ----------------
__global__ __launch_bounds__(256) void cvt_bf16(const float* __restrict__ s,
                                                u16* __restrict__ d, int n4){
    int i = blockIdx.x*256 + threadIdx.x;
    if (i < n4){
        float4 v = ((const float4*)s)[i];
        ushort4 o;
        o.x = f2b(v.x); o.y = f2b(v.y); o.z = f2b(v.z); o.w = f2b(v.w);
        ((ushort4*)d)[i] = o;
    }
}

// ---- W_ih cvt with row permutation: out row (unit*4+gate) = in row (gate*128+unit) ----
__global__ __launch_bounds__(192) void cvt_wih_perm(const float* __restrict__ s,
                                                    u16* __restrict__ d){
    int r = blockIdx.x;               // 0..511 input row
    int j = threadIdx.x;              // 0..191 float4 within row
    int g = r >> 7, u = r & 127;
    int ro = u * 4 + g;
    float4 v = ((const float4*)(s + (size_t)r * 768))[j];
    ushort4 o;
    o.x = f2b(v.x); o.y = f2b(v.y); o.z = f2b(v.z); o.w = f2b(v.w);
    ((ushort4*)(d + (size_t)ro * 768))[j] = o;
}

// ---- W_hh cvt with the same row permutation, 128 cols, bf16 out ----
__global__ __launch_bounds__(256) void cvt_whh_perm(const float* __restrict__ s,
                                                    u16* __restrict__ d){
    int idx = blockIdx.x*256 + threadIdx.x;   // 0..16383
    if (idx >= 512*32) return;
    int r = idx >> 5, j = idx & 31;           // row, float4 within row
    int g = r >> 7, u = r & 127;
    int ro = u * 4 + g;
    float4 v = ((const float4*)(s + (size_t)r * 128))[j];
    ushort4 o;
    o.x = f2b(v.x); o.y = f2b(v.y); o.z = f2b(v.z); o.w = f2b(v.w);
    ((ushort4*)(d + (size_t)ro * 128))[j] = o;
}

// ---------------- embedding-gather + input projection GEMM ----------------
// pre written PAIRED in the LANE-EXACT layout of the column-quadrant lstm_rec:
//   idx = ((blk*(Tdim/2) + (t>>1))*512 + tidL)*8 + ((t&1)^dirO)*4 + gate
// (two consecutive time-steps share one 16B short8 per lane; halves are stored
//  in DIRECTION order so the lstm consumes half = step&1 statically).
// tidL = wL*64 + (uL&3)*16 + (uL&12) + cL  (cell: unit uu=wL*16+uL, chain cL).
// word: blk = dir*8  + (batch>>2), cL = batch&3, Tdim=1024
// sent: blk = dir*128 + (sent>>2), cL = sent&3,  Tdim=64
__global__ __launch_bounds__(256) void gemm_embed(
    const u16* __restrict__ E, const int* __restrict__ tok,
    const u16* __restrict__ Wt, const float* __restrict__ bf_,
    const float* __restrict__ bb_, u16* __restrict__ pre, int sentMode)
{
    __shared__ __align__(16) u16 Asm[128*32];
    __shared__ __align__(16) u16 Bsm[128*32];
    const int m0 = blockIdx.x * 128, n0 = blockIdx.y * 128;
    const int tid = threadIdx.x;
    const int ar = tid >> 2, ch = (tid & 3) * 8;
    const u16* ap0 = E + (size_t)tok[m0 + ar] * 768 + ch;
    const u16* ap1 = E + (size_t)tok[m0 + 64 + ar] * 768 + ch;
    const u16* bp0 = Wt + (size_t)(n0 + ar) * 768 + ch;
    const u16* bp1 = Wt + (size_t)(n0 + 64 + ar) * 768 + ch;
    const int lane = tid & 63, wave = tid >> 6;
    const int wm = (wave >> 1) * 64, wn = (wave & 1) * 64;
    const int qr = lane >> 4, lr = lane & 15;
    f32x4 acc[4][4] = {};
    for (int k0 = 0; k0 < 768; k0 += 32){
        __syncthreads();
        *(short8*)&Asm[ar*32 + ch]      = *(const short8*)(ap0 + k0);
        *(short8*)&Asm[(64+ar)*32 + ch] = *(const short8*)(ap1 + k0);
        *(short8*)&Bsm[ar*32 + ch]      = *(const short8*)(bp0 + k0);
        *(short8*)&Bsm[(64+ar)*32 + ch] = *(const short8*)(bp1 + k0);
        __syncthreads();
        short8 af[4], bfr[4];
        #pragma unroll
        for (int i = 0; i < 4; ++i){
            af[i]  = *(const short8*)&Asm[(wm + i*16 + lr)*32 + qr*8];
            bfr[i] = *(const short8*)&Bsm[(wn + i*16 + lr)*32 + qr*8];
        }
        #pragma unroll
        for (int i = 0; i < 4; ++i)
            #pragma unroll
            for (int j = 0; j < 4; ++j)
                acc[i][j] = __builtin_amdgcn_mfma_f32_16x16x32_bf16(af[i], bfr[j], acc[i][j], 0, 0, 0);
    }
    #pragma unroll
    for (int j = 0; j < 4; ++j){
        int col = n0 + wn + j*16 + lr;
        int dirO = col >> 9, pcol = col & 511;
        int uu = pcol >> 2, gg = pcol & 3;
        float bias = (dirO ? bb_ : bf_)[gg*128 + uu];
        int wL = uu >> 4, uL = uu & 15;
        int tidPart = wL*64 + (uL & 3)*16 + (uL & 12);   // + cL at use site
        #pragma unroll
        for (int i = 0; i < 4; ++i){
            #pragma unroll
            for (int r = 0; r < 4; ++r){
                int mrow = m0 + wm + i*16 + qr*4 + r;
                int blk, t, cL, Tdim;
                if (sentMode){ int s = mrow >> 6;  t = mrow & 63;   blk = (dirO<<7) + (s >> 2); cL = s & 3; Tdim = 64; }
                else         { int b = mrow >> 10; t = mrow & 1023; blk = (dirO<<3) + (b >> 2); cL = b & 3; Tdim = 1024; }
                size_t idx = (((size_t)blk * (Tdim >> 1) + (t >> 1)) * 512 + (tidPart + cL)) * 8
                           + (((t & 1) ^ dirO) << 2) + gg;
                pre[idx] = f2b(acc[i][j][r] + bias);
            }
        }
    }
}

// ---------------- batched MFMA LSTM recurrence (column-quadrant layout) ----------------
// r10 (637us, ~1493 cyc/step) left ~400cyc of vmcnt/scheduling slack. r11:
//  (1) PAIRED pre loads: one short8 = 2 steps (layout change in gemm_embed).
//      Loads/step 1 -> 0.5 and prefetch distance 3 -> 8 steps: the counted
//      vmcnt has real slack even with per-step stores sharing the counter.
//  (2) sched_barrier(0x77) (ALU|VALU|SALU|VMEM may cross, DS blocked) instead
//      of sched_barrier(0): preserves the LDS ordering that correctness needs,
//      lets pointer math + the pair load hoist across the barrier window.
//  (3) 8-step unrolled body for the static slot/half schedule.
// MFMA mapping, select, gates, po store, hb swizzle: identical to r10 (passed).
__global__ __launch_bounds__(512)
__attribute__((amdgpu_waves_per_eu(2)))
void lstm_rec(
    const u16* __restrict__ preW, const u16* __restrict__ preS,
    const u16* __restrict__ Whp,     // [4][512][128] bf16: wordF, wordB, sentF, sentB
    float* __restrict__ fo, float* __restrict__ fs)
{
    const int bg = blockIdx.x;
    const u16* preBlk; const u16* wh; float* out;
    int T, dir, grpb;
    if (bg < 16){                     // word: 8 groups x 2 dirs, T=1024
        dir = bg >> 3; grpb = bg & 7; T = 1024;
        preBlk = preW + (size_t)bg * 512 * 4096;     // 512 pairs x 4096 u16
        wh = Whp + (size_t)dir*512*128; out = fo;
    } else {                          // sent: 128 groups x 2 dirs, T=64
        int sg = bg - 16; dir = sg >> 7; grpb = sg & 127; T = 64;
        preBlk = preS + (size_t)sg * 32 * 4096;      // 32 pairs x 4096 u16
        wh = Whp + (size_t)(2+dir)*512*128; out = fs;
    }
    const int tid  = threadIdx.x;
    const int w    = tid >> 6, lane = tid & 63;
    const int lr = lane & 15, qr = lane >> 4;
    const int t0 = dir ? (T-1) : 0;
    const int dt = dir ? -1 : 1;

    // A-fragments: 64 W_hh rows per wave, PINNED in VGPRs (r6-proven pattern)
    short8 aw[4][4];
    #pragma unroll
    for (int i = 0; i < 4; ++i)
        #pragma unroll
        for (int kk = 0; kk < 4; ++kk)
            asm volatile("global_load_dwordx4 %0, %1, off"
                         : "=v"(aw[i][kk])
                         : "v"(wh + (size_t)(w*64 + i*16 + lr)*128 + kk*32 + qr*8));
    asm volatile("s_waitcnt vmcnt(0)");
    __builtin_amdgcn_sched_barrier(0);

    __shared__ __align__(16) u16 hb[2][512];   // bf16 h: [chain 0..3][unit 0..127], swizzled (2KB)
    for (int k = tid; k < 1024; k += 512) ((u16*)hb)[k] = 0;

    // this lane's cell: chain cL = lr&3, unit u = w*16 + (lr>>2)*4 + qr
    const int cL = lr & 3;
    const int u  = w*16 + (lr >> 2)*4 + qr;
    const int hbW   = cL*128 + (u ^ (cL << 4));          // swizzled h write
    const int rbase = cL*128;                            // bfr read row base
    const int rxor  = cL << 4;                           // bfr read swizzle
    const bool s2 = (lr & 4) != 0, s3 = (lr & 8) != 0;   // acc-select masks (loop-invariant)

    const int chainG = grpb*4 + cL;
    float* po = out + ((size_t)chainG*T + t0)*256 + dir*128 + u;
    const long ostep = (long)dt * 256;

    // paired pre prefetch: 4 static slots, each holding TWO steps (16B/lane).
    const int  t0pair = dir ? (T/2 - 1) : 0;
    const long ppstep = (long)dt * 4096;
    const u16* pp = preBlk + (long)t0pair * 4096 + tid*8;
    short8 buf[4];
    buf[0] = *(const short8*)pp;
    buf[1] = *(const short8*)(pp + ppstep);
    buf[2] = *(const short8*)(pp + 2*ppstep);
    buf[3] = *(const short8*)(pp + 3*ppstep);
    pp += 4*ppstep;

    float cst = 0.f;
    __syncthreads();

#define LSTM_STEP(J, SLOT, HALF, DOLOAD) do {                                 \
    short8 bfr[4];                                                            \
    _Pragma("unroll")                                                         \
    for (int kk = 0; kk < 4; ++kk)                                            \
        bfr[kk] = *(const short8*)&hb[(J)&1][rbase + ((kk*32 + qr*8) ^ rxor)];\
    ushort4 pc;                                                               \
    pc.x = (u16)buf[SLOT][(HALF)*4+0]; pc.y = (u16)buf[SLOT][(HALF)*4+1];     \
    pc.z = (u16)buf[SLOT][(HALF)*4+2]; pc.w = (u16)buf[SLOT][(HALF)*4+3];     \
    if (DOLOAD){ buf[SLOT] = *(const short8*)pp; pp += ppstep; }              \
    f32x4 a0 = {}, a1 = {}, a2 = {}, a3 = {};                                 \
    _Pragma("unroll")                                                         \
    for (int kk = 0; kk < 4; ++kk){                                           \
        a0 = __builtin_amdgcn_mfma_f32_16x16x32_bf16(aw[0][kk], bfr[kk], a0, 0, 0, 0); \
        a1 = __builtin_amdgcn_mfma_f32_16x16x32_bf16(aw[1][kk], bfr[kk], a1, 0, 0, 0); \
        a2 = __builtin_amdgcn_mfma_f32_16x16x32_bf16(aw[2][kk], bfr[kk], a2, 0, 0, 0); \
        a3 = __builtin_amdgcn_mfma_f32_16x16x32_bf16(aw[3][kk], bfr[kk], a3, 0, 0, 0); \
    }                                                                         \
    float m0 = s3 ? (s2 ? a3[0] : a2[0]) : (s2 ? a1[0] : a0[0]);              \
    float m1 = s3 ? (s2 ? a3[1] : a2[1]) : (s2 ? a1[1] : a0[1]);              \
    float m2 = s3 ? (s2 ? a3[2] : a2[2]) : (s2 ? a1[2] : a0[2]);              \
    float m3 = s3 ? (s2 ? a3[3] : a2[3]) : (s2 ? a1[3] : a0[3]);              \
    float g0 = b2f(pc.x) + m0, g1 = b2f(pc.y) + m1;                           \
    float g2 = b2f(pc.z) + m2, g3 = b2f(pc.w) + m3;                           \
    float gi = sigm(g0), gf = sigm(g1);                                       \
    float gg = tanhf2(g2), go = sigm(g3);                                     \
    float c = gf*cst + gi*gg; cst = c;                                        \
    float h = go*tanhf2(c);                                                   \
    po[0] = h;                                                                \
    po += ostep;                                                              \
    hb[((J)&1)^1][hbW] = f2b(h);                                              \
    __builtin_amdgcn_sched_barrier(0x77);                                     \
    asm volatile("s_waitcnt lgkmcnt(0)");                                     \
    __builtin_amdgcn_s_barrier();                                             \
    __builtin_amdgcn_sched_barrier(0x77);                                     \
} while(0)

    for (int itBase = 0; itBase < T; itBase += 8){
        LSTM_STEP(0, 0, 0, 0);
        LSTM_STEP(1, 0, 1, 1);
        LSTM_STEP(2, 1, 0, 0);
        LSTM_STEP(3, 1, 1, 1);
        LSTM_STEP(4, 2, 0, 0);
        LSTM_STEP(5, 2, 1, 1);
        LSTM_STEP(6, 3, 0, 0);
        LSTM_STEP(7, 3, 1, 1);
    }
#undef LSTM_STEP
}

// ---------------- gate GEMM + blend epilogue ----------------
// gamma = sigmoid([fo|fs] @ gW^T + gb); out = gamma*fo + (1-gamma)*fs
__global__ __launch_bounds__(256) void gemm_gate(
    const u16* __restrict__ gW, const float* __restrict__ gb,
    const float* __restrict__ fo, const float* __restrict__ fs,
    float* __restrict__ out)
{
    __shared__ __align__(16) u16 Asm[128*32];
    __shared__ __align__(16) u16 Bsm[128*32];
    const int m0 = blockIdx.x * 128, n0 = blockIdx.y * 128;
    const int tid = threadIdx.x;
    const int ar = tid >> 2, ch = (tid & 3) * 8;
    const float* af0 = fo + (size_t)(m0 + ar) * 256 + ch;
    const float* af1 = fo + (size_t)(m0 + 64 + ar) * 256 + ch;
    const float* as0 = fs + (size_t)(m0 + ar) * 256 + ch;
    const float* as1 = fs + (size_t)(m0 + 64 + ar) * 256 + ch;
    const u16* bp0 = gW + (size_t)(n0 + ar) * 512 + ch;
    const u16* bp1 = gW + (size_t)(n0 + 64 + ar) * 512 + ch;
    const int lane = tid & 63, wave = tid >> 6;
    const int wm = (wave >> 1) * 64, wn = (wave & 1) * 64;
    const int qr = lane >> 4, lr = lane & 15;
    f32x4 acc[4][4] = {};
    for (int k0 = 0; k0 < 512; k0 += 32){
        __syncthreads();
        const float* s0 = (k0 < 256) ? (af0 + k0) : (as0 + (k0 - 256));
        const float* s1 = (k0 < 256) ? (af1 + k0) : (as1 + (k0 - 256));
        float4 x0 = ((const float4*)s0)[0], x1 = ((const float4*)s0)[1];
        float4 y0 = ((const float4*)s1)[0], y1 = ((const float4*)s1)[1];
        ushort4 a0; a0.x=f2b(x0.x); a0.y=f2b(x0.y); a0.z=f2b(x0.z); a0.w=f2b(x0.w);
        ushort4 a1; a1.x=f2b(x1.x); a1.y=f2b(x1.y); a1.z=f2b(x1.z); a1.w=f2b(x1.w);
        ushort4 b0; b0.x=f2b(y0.x); b0.y=f2b(y0.y); b0.z=f2b(y0.z); b0.w=f2b(y0.w);
        ushort4 b1; b1.x=f2b(y1.x); b1.y=f2b(y1.y); b1.z=f2b(y1.z); b1.w=f2b(y1.w);
        *(ushort4*)&Asm[ar*32 + ch]          = a0;
        *(ushort4*)&Asm[ar*32 + ch + 4]      = a1;
        *(ushort4*)&Asm[(64+ar)*32 + ch]     = b0;
        *(ushort4*)&Asm[(64+ar)*32 + ch + 4] = b1;
        *(short8*)&Bsm[ar*32 + ch]      = *(const short8*)(bp0 + k0);
        *(short8*)&Bsm[(64+ar)*32 + ch] = *(const short8*)(bp1 + k0);
        __syncthreads();
        short8 af[4], bfr[4];
        #pragma unroll
        for (int i = 0; i < 4; ++i){
            af[i]  = *(const short8*)&Asm[(wm + i*16 + lr)*32 + qr*8];
            bfr[i] = *(const short8*)&Bsm[(wn + i*16 + lr)*32 + qr*8];
        }
        #pragma unroll
        for (int i = 0; i < 4; ++i)
            #pragma unroll
            for (int j = 0; j < 4; ++j)
                acc[i][j] = __builtin_amdgcn_mfma_f32_16x16x32_bf16(af[i], bfr[j], acc[i][j], 0, 0, 0);
    }
    #pragma unroll
    for (int j = 0; j < 4; ++j){
        int col = n0 + wn + j*16 + lr;   // 0..255
        float bias = gb[col];
        #pragma unroll
        for (int i = 0; i < 4; ++i){
            #pragma unroll
            for (int r = 0; r < 4; ++r){
                int row = m0 + wm + i*16 + qr*4 + r;
                size_t o = (size_t)row*256 + col;
                float gamma = sigm(acc[i][j][r] + bias);
                out[o] = gamma * fo[o] + (1.f - gamma) * fs[o];
            }
        }
    }
}

extern "C" void kernel_launch(void* const* d_in, const int* in_sizes, int n_in,
                              void* d_out, int out_size, void* d_ws, size_t ws_size,
                              hipStream_t stream)
{
    (void)in_sizes; (void)n_in; (void)out_size; (void)ws_size;
    const int*   wordTok = (const int*)d_in[0];
    const int*   sentTok = (const int*)d_in[1];
    const float* E       = (const float*)d_in[3];
    const float* WihWf   = (const float*)d_in[4];
    const float* WhhWf   = (const float*)d_in[5];
    const float* bWf     = (const float*)d_in[6];
    const float* WihWb   = (const float*)d_in[7];
    const float* WhhWb   = (const float*)d_in[8];
    const float* bWb     = (const float*)d_in[9];
    const float* WihSf   = (const float*)d_in[10];
    const float* WhhSf   = (const float*)d_in[11];
    const float* bSf     = (const float*)d_in[12];
    const float* WihSb   = (const float*)d_in[13];
    const float* WhhSb   = (const float*)d_in[14];
    const float* bSb     = (const float*)d_in[15];
    const float* gateW   = (const float*)d_in[16];
    const float* gateB   = (const float*)d_in[17];
    float* out = (float*)d_out;

    char* w = (char*)d_ws;
    u16* Eb   = (u16*)w;  w += (size_t)30522*768*2;
    u16* Ww   = (u16*)w;  w += (size_t)1024*768*2;
    u16* Ws_  = (u16*)w;  w += (size_t)1024*768*2;
    u16* gWb  = (u16*)w;  w += (size_t)256*512*2;
    u16* preW = (u16*)w;  w += (size_t)32768*1024*2;
    u16* preS = (u16*)w;  w += (size_t)32768*1024*2;
    float* fo = (float*)w; w += (size_t)32768*256*4;
    float* fs = (float*)w; w += (size_t)32768*256*4;
    u16* Whp  = (u16*)w;  w += (size_t)4*512*128*2;

    const int nE4 = 30522*768/4;
    cvt_bf16<<<(nE4+255)/256, 256, 0, stream>>>(E, Eb, nE4);
    cvt_wih_perm<<<512, 192, 0, stream>>>(WihWf, Ww);
    cvt_wih_perm<<<512, 192, 0, stream>>>(WihWb, Ww + 512*768);
    cvt_wih_perm<<<512, 192, 0, stream>>>(WihSf, Ws_);
    cvt_wih_perm<<<512, 192, 0, stream>>>(WihSb, Ws_ + 512*768);
    const int nG4 = 256*512/4;
    cvt_bf16<<<(nG4+255)/256, 256, 0, stream>>>(gateW, gWb, nG4);
    cvt_whh_perm<<<64, 256, 0, stream>>>(WhhWf, Whp);
    cvt_whh_perm<<<64, 256, 0, stream>>>(WhhWb, Whp + 512*128);
    cvt_whh_perm<<<64, 256, 0, stream>>>(WhhSf, Whp + 2*512*128);
    cvt_whh_perm<<<64, 256, 0, stream>>>(WhhSb, Whp + 3*512*128);

    gemm_embed<<<dim3(256,8), 256, 0, stream>>>(Eb, wordTok, Ww, bWf, bWb, preW, 0);
    gemm_embed<<<dim3(256,8), 256, 0, stream>>>(Eb, sentTok, Ws_, bSf, bSb, preS, 1);
    lstm_rec<<<272, 512, 0, stream>>>(preW, preS, Whp, fo, fs);
    gemm_gate<<<dim3(256,2), 256, 0, stream>>>(gWb, gateB, fo, fs, out);
}